// Round 1
// baseline (105.654 us; speedup 1.0000x reference)
//
#include <hip/hip_runtime.h>

#define BB 16
#define NN 8
#define CC 3
#define HH 256
#define WW 256
#define PLANE (HH * WW)          // 65536
#define SLICE (CC * PLANE)       // 196608 elems per (b,n)

// One thread = 4 consecutive x pixels, all 3 channels.
// tid layout: x4 = tid & 63 (x = x4*4), y = (tid>>6) & 255, bn = tid >> 14.
// bn is uniform within a 256-thread block (bn changes every 64 blocks).
__global__ __launch_bounds__(256) void warp_kernel(
    const float* __restrict__ img,   // [B][C][H][W]
    const float* __restrict__ tf,    // [B][N][6]
    float* __restrict__ out,         // [B][N][C][H][W]
    int* __restrict__ flags)         // [B*N] nonzero-seen flags
{
    int tid = blockIdx.x * 256 + threadIdx.x;
    int x  = (tid & 63) << 2;
    int y  = (tid >> 6) & 255;
    int bn = tid >> 14;
    int b  = bn >> 3;

    const float* M = tf + bn * 6;
    float a  = M[0], bm = M[1], tx = M[2];
    float c  = M[3], d  = M[4], ty = M[5];
    float det = a * d - bm * c;
    float ia  =  d / det;
    float ib  = -bm / det;
    float ic  = -c / det;
    float idm =  a / det;

    const float* imgb = img + (size_t)b * SLICE;

    float res[CC][4];
    bool nz = false;
    float dy = (float)y - ty;

#pragma unroll
    for (int p = 0; p < 4; ++p) {
        float dx = (float)(x + p) - tx;
        float sx = ia * dx + ib * dy;
        float sy = ic * dx + idm * dy;
        float x0f = floorf(sx);
        float y0f = floorf(sy);
        float wx = sx - x0f;
        float wy = sy - y0f;
        int x0 = (int)x0f;
        int y0 = (int)y0f;

        float w00 = (1.f - wx) * (1.f - wy);
        float w01 = wx * (1.f - wy);
        float w10 = (1.f - wx) * wy;
        float w11 = wx * wy;

        bool vx0 = (x0 >= 0)     & (x0 < WW);
        bool vx1 = (x0 + 1 >= 0) & (x0 + 1 < WW);
        bool vy0 = (y0 >= 0)     & (y0 < HH);
        bool vy1 = (y0 + 1 >= 0) & (y0 + 1 < HH);

        int xc0 = min(max(x0, 0), WW - 1);
        int xc1 = min(max(x0 + 1, 0), WW - 1);
        int yc0 = min(max(y0, 0), HH - 1);
        int yc1 = min(max(y0 + 1, 0), HH - 1);

        int i00 = yc0 * WW + xc0;
        int i01 = yc0 * WW + xc1;
        int i10 = yc1 * WW + xc0;
        int i11 = yc1 * WW + xc1;

#pragma unroll
        for (int ch = 0; ch < CC; ++ch) {
            const float* pc = imgb + ch * PLANE;
            float v00 = (vx0 && vy0) ? pc[i00] : 0.f;
            float v01 = (vx1 && vy0) ? pc[i01] : 0.f;
            float v10 = (vx0 && vy1) ? pc[i10] : 0.f;
            float v11 = (vx1 && vy1) ? pc[i11] : 0.f;
            float o = v00 * w00 + v01 * w01 + v10 * w10 + v11 * w11;
            res[ch][p] = o;
            nz |= (o != 0.f);
        }
    }

    size_t base = (size_t)bn * SLICE + (size_t)y * WW + x;
#pragma unroll
    for (int ch = 0; ch < CC; ++ch) {
        *reinterpret_cast<float4*>(out + base + (size_t)ch * PLANE) =
            make_float4(res[ch][0], res[ch][1], res[ch][2], res[ch][3]);
    }

    // all-zero detection: one atomic per block (bn is block-uniform)
    __shared__ int s_nz;
    if (threadIdx.x == 0) s_nz = 0;
    __syncthreads();
    if (nz) s_nz = 1;            // benign race: all writers store 1
    __syncthreads();
    if (threadIdx.x == 0 && s_nz) atomicOr(&flags[bn], 1);
}

// If a (b,n) slice produced no nonzero element, overwrite it with -1.
// Never triggers with near-identity transforms -> 128 blocks early-exit.
__global__ __launch_bounds__(256) void fixup_kernel(
    float* __restrict__ out, const int* __restrict__ flags)
{
    int bn = blockIdx.x;
    if (flags[bn] != 0) return;
    float4 m1 = make_float4(-1.f, -1.f, -1.f, -1.f);
    float4* o4 = reinterpret_cast<float4*>(out + (size_t)bn * SLICE);
    for (int i = threadIdx.x; i < SLICE / 4; i += 256) o4[i] = m1;
}

extern "C" void kernel_launch(void* const* d_in, const int* in_sizes, int n_in,
                              void* d_out, int out_size, void* d_ws, size_t ws_size,
                              hipStream_t stream) {
    (void)in_sizes; (void)n_in; (void)out_size; (void)ws_size;
    const float* img = (const float*)d_in[0];
    const float* tf  = (const float*)d_in[1];
    float* out = (float*)d_out;
    int* flags = (int*)d_ws;

    hipMemsetAsync(flags, 0, BB * NN * sizeof(int), stream);

    int total_threads = BB * NN * HH * WW / 4;   // 2,097,152
    warp_kernel<<<total_threads / 256, 256, 0, stream>>>(img, tf, out, flags);
    fixup_kernel<<<BB * NN, 256, 0, stream>>>(out, flags);
}